// Round 1
// baseline (426.414 us; speedup 1.0000x reference)
//
#include <hip/hip_runtime.h>
#include <stdint.h>

#define F 128

struct EdgeRec { int src; float norm; };

// ---- 1. in-degree histogram over col ----
__global__ void deg_kernel(const int* __restrict__ col, int* __restrict__ deg, int E) {
    int e = blockIdx.x * blockDim.x + threadIdx.x;
    if (e < E) atomicAdd(&deg[col[e]], 1);
}

// ---- 2. deg^{-1/2} with zero-degree -> 1 ----
__global__ void dinv_kernel(const int* __restrict__ deg, float* __restrict__ dinv, int N) {
    int n = blockIdx.x * blockDim.x + threadIdx.x;
    if (n < N) {
        int d = deg[n];
        if (d < 1) d = 1;
        dinv[n] = rsqrtf((float)d);
    }
}

// ---- 3. exclusive scan of deg -> start[0..N], single block of 1024 ----
__global__ void scan_kernel(const int* __restrict__ deg, int* __restrict__ start, int N) {
    __shared__ int sm[1024];
    __shared__ int carry_s;
    int tid = threadIdx.x;
    if (tid == 0) carry_s = 0;
    __syncthreads();
    for (int base = 0; base < N; base += 1024) {
        int i = base + tid;
        int v = (i < N) ? deg[i] : 0;
        int val = v;
        sm[tid] = val;
        __syncthreads();
        for (int off = 1; off < 1024; off <<= 1) {
            int t = 0;
            if (tid >= off) t = sm[tid - off];
            __syncthreads();
            val += t;
            sm[tid] = val;
            __syncthreads();
        }
        int carry = carry_s;
        if (i < N) start[i] = carry + val - v;   // exclusive
        __syncthreads();
        if (tid == 1023) carry_s = carry + val;
        __syncthreads();
    }
    if (tid == 0) start[N] = carry_s;
}

// ---- 4. counting-sort edges by target node; fuse norm computation ----
__global__ void bucket_kernel(const int* __restrict__ row, const int* __restrict__ col,
                              const float* __restrict__ dinv, const int* __restrict__ start,
                              int* __restrict__ cursor, EdgeRec* __restrict__ edges, int E) {
    int e = blockIdx.x * blockDim.x + threadIdx.x;
    if (e < E) {
        int c = col[e];
        int r = row[e];
        int pos = start[c] + atomicAdd(&cursor[c], 1);
        EdgeRec rec;
        rec.src  = r;
        rec.norm = dinv[r] * dinv[c];
        edges[pos] = rec;
    }
}

// ---- 5. one propagation layer: wave per target node, pure gather ----
__global__ __launch_bounds__(256) void layer_kernel(
        const float* __restrict__ cur_in, float* __restrict__ cur_out,
        float* __restrict__ update, const int* __restrict__ start,
        const EdgeRec* __restrict__ edges, const float* __restrict__ kv,
        int layer, int N) {
    int wid  = (blockIdx.x * blockDim.x + threadIdx.x) >> 6;  // node id (wave per node)
    int lane = threadIdx.x & 63;
    if (wid >= N) return;
    float tk = tanhf(kv[layer]);
    int s = start[wid];
    int t = start[wid + 1];
    float2 acc = make_float2(0.f, 0.f);
    EdgeRec r0;
    if (s < t) r0 = edges[s];
    for (int e = s; e < t; ++e) {
        EdgeRec rn = r0;
        if (e + 1 < t) rn = edges[e + 1];          // prefetch next edge record
        float2 v = ((const float2*)(cur_in + (size_t)r0.src * F))[lane];
        acc.x += r0.norm * v.x;
        acc.y += r0.norm * v.y;
        r0 = rn;
    }
    float2 c = ((const float2*)(cur_in + (size_t)wid * F))[lane];
    float2 nc = make_float2(c.x - acc.x, c.y - acc.y);
    ((float2*)(cur_out + (size_t)wid * F))[lane] = nc;
    float2* up = (float2*)(update + (size_t)wid * F);
    float2 u = up[lane];
    u.x += tk * nc.x;
    u.y += tk * nc.y;
    up[lane] = u;
}

// ---- 6. epilogue: h = c*update + (1-c)*x; out = relu(h @ W^T + b) ----
#define TM 32
#define KC 32
__global__ __launch_bounds__(256) void final_kernel(
        const float* __restrict__ x, const float* __restrict__ update,
        const float* __restrict__ W, const float* __restrict__ bias,
        const float* __restrict__ wt, float* __restrict__ out, int N) {
    __shared__ float hs[TM * F];       // 16 KB
    __shared__ float Wl[KC * 129];     // padded stride kills bank conflicts
    int tid  = threadIdx.x;
    int row0 = blockIdx.x * TM;
    float cst  = 1.f / (1.f + __expf(-wt[0]));
    float cst1 = 1.f - cst;
    // stage blended h tile
    for (int j = tid; j < TM * F; j += 256) {
        int r = j >> 7, k = j & 127;
        int gr = row0 + r;
        float v = 0.f;
        if (gr < N) {
            size_t idx = (size_t)gr * F + k;
            v = cst * update[idx] + cst1 * x[idx];
        }
        hs[j] = v;
    }
    int c  = tid & 127;
    int rg = tid >> 7;                 // 0..1 -> rows rg*16 .. rg*16+15
    float acc[16];
#pragma unroll
    for (int i = 0; i < 16; ++i) acc[i] = 0.f;
    for (int kc = 0; kc < F; kc += KC) {
        __syncthreads();               // hs ready (iter 0) / prev compute done
        // stage W chunk transposed: Wl[kk][c2] = W[c2][kc+kk]
        for (int j = tid; j < KC * F; j += 256) {
            int c2 = j >> 5, kk = j & 31;
            Wl[kk * 129 + c2] = W[(size_t)c2 * F + kc + kk];
        }
        __syncthreads();
#pragma unroll 8
        for (int kk = 0; kk < KC; ++kk) {
            float w = Wl[kk * 129 + c];
#pragma unroll
            for (int r = 0; r < 16; ++r)
                acc[r] += hs[(rg * 16 + r) * F + kc + kk] * w;
        }
    }
    float bv = bias[c];
#pragma unroll
    for (int r = 0; r < 16; ++r) {
        int gr = row0 + rg * 16 + r;
        if (gr < N) {
            float v = acc[r] + bv;
            out[(size_t)gr * F + c] = v > 0.f ? v : 0.f;
        }
    }
}

extern "C" void kernel_launch(void* const* d_in, const int* in_sizes, int n_in,
                              void* d_out, int out_size, void* d_ws, size_t ws_size,
                              hipStream_t stream) {
    const float* x   = (const float*)d_in[0];
    const int*   ei  = (const int*)d_in[1];
    const float* kv  = (const float*)d_in[2];
    const float* wt  = (const float*)d_in[3];
    const float* W   = (const float*)d_in[4];
    const float* b   = (const float*)d_in[5];
    float* out = (float*)d_out;

    const int E = in_sizes[1] / 2;
    const int N = in_sizes[0] / F;
    const int L = in_sizes[2];
    const int* row = ei;           // edge_index[0]
    const int* col = ei + E;       // edge_index[1]

    // workspace carve (256B aligned)
    size_t off = 0;
    auto alloc = [&](size_t bytes) {
        void* p = (char*)d_ws + off;
        off += (bytes + 255) & ~(size_t)255;
        return p;
    };
    int*     deg    = (int*)alloc((size_t)N * 4);
    int*     cursor = (int*)alloc((size_t)N * 4);
    int*     start  = (int*)alloc((size_t)(N + 1) * 4);
    float*   dinv   = (float*)alloc((size_t)N * 4);
    EdgeRec* edges  = (EdgeRec*)alloc((size_t)E * sizeof(EdgeRec));
    float*   cur0   = (float*)alloc((size_t)N * F * 4);
    float*   cur1   = (float*)alloc((size_t)N * F * 4);
    float*   update = (float*)alloc((size_t)N * F * 4);
    (void)ws_size;

    hipMemsetAsync(deg,    0, (size_t)N * 4, stream);
    hipMemsetAsync(cursor, 0, (size_t)N * 4, stream);
    hipMemsetAsync(update, 0, (size_t)N * F * 4, stream);
    hipMemcpyAsync(cur0, x, (size_t)N * F * 4, hipMemcpyDeviceToDevice, stream);

    deg_kernel<<<(E + 255) / 256, 256, 0, stream>>>(col, deg, E);
    dinv_kernel<<<(N + 255) / 256, 256, 0, stream>>>(deg, dinv, N);
    scan_kernel<<<1, 1024, 0, stream>>>(deg, start, N);
    bucket_kernel<<<(E + 255) / 256, 256, 0, stream>>>(row, col, dinv, start, cursor, edges, E);

    float* bufs[2] = {cur0, cur1};
    for (int i = 0; i < L; ++i) {
        layer_kernel<<<(N + 3) / 4, 256, 0, stream>>>(
            bufs[i & 1], bufs[(i + 1) & 1], update, start, edges, kv, i, N);
    }

    final_kernel<<<(N + TM - 1) / TM, 256, 0, stream>>>(x, update, W, b, wt, out, N);
}